// Round 3
// baseline (777.870 us; speedup 1.0000x reference)
//
#include <hip/hip_runtime.h>
#include <hip/hip_bf16.h>
#include <stdint.h>

#define B_  2
#define T_  2048
#define C_  1024
#define H_  16
#define HD_ 64
#define M_  4096   // B*T
#define FF_ 4096

typedef unsigned short ushort_t;
typedef __bf16 bf16x8 __attribute__((ext_vector_type(8)));
typedef float  f32x4  __attribute__((ext_vector_type(4)));

__device__ inline ushort_t f2bf(float f) {
  uint32_t u = __builtin_bit_cast(uint32_t, f);
  u += 0x7fffu + ((u >> 16) & 1u);
  return (ushort_t)(u >> 16);
}

// async global->LDS, 16B per lane (dwordx4 variant)
__device__ inline void gload_lds16(const void* g, void* l) {
  __builtin_amdgcn_global_load_lds(
      (const __attribute__((address_space(1))) uint32_t*)g,
      (__attribute__((address_space(3))) uint32_t*)l, 16, 0, 0);
}

// ---------------------------------------------------------------- LayerNorm
__global__ __launch_bounds__(256) void lnorm_kernel(
    const float* __restrict__ x, const float* __restrict__ g,
    const float* __restrict__ b, ushort_t* __restrict__ o) {
  int row = blockIdx.x;
  int tid = threadIdx.x;
  const float4* xr = (const float4*)(x + (size_t)row * C_);
  float4 xv = xr[tid];
  float s  = xv.x + xv.y + xv.z + xv.w;
  float s2 = xv.x*xv.x + xv.y*xv.y + xv.z*xv.z + xv.w*xv.w;
#pragma unroll
  for (int off = 32; off; off >>= 1) {
    s  += __shfl_down(s,  off);
    s2 += __shfl_down(s2, off);
  }
  __shared__ float rs[4], rq[4];
  int wid = tid >> 6;
  if ((tid & 63) == 0) { rs[wid] = s; rq[wid] = s2; }
  __syncthreads();
  float tot  = rs[0] + rs[1] + rs[2] + rs[3];
  float tot2 = rq[0] + rq[1] + rq[2] + rq[3];
  float mu   = tot * (1.0f / C_);
  float var  = tot2 * (1.0f / C_) - mu * mu;
  float rstd = rsqrtf(var + 1e-5f);
  float4 gv = ((const float4*)g)[tid];
  float4 bv = ((const float4*)b)[tid];
  float y0 = (xv.x - mu) * rstd * gv.x + bv.x;
  float y1 = (xv.y - mu) * rstd * gv.y + bv.y;
  float y2 = (xv.z - mu) * rstd * gv.z + bv.z;
  float y3 = (xv.w - mu) * rstd * gv.w + bv.w;
  uint2 pk;
  pk.x = (uint32_t)f2bf(y0) | ((uint32_t)f2bf(y1) << 16);
  pk.y = (uint32_t)f2bf(y2) | ((uint32_t)f2bf(y3) << 16);
  *(uint2*)(o + (size_t)row * C_ + tid * 4) = pk;
}

// ------------------------------------------- transpose + f32->bf16 cast of W
// W [K][N] f32  ->  Wt [N][K] bf16
__global__ __launch_bounds__(256) void tcast_kernel(
    const float* __restrict__ W, ushort_t* __restrict__ Wt, int K, int N) {
  __shared__ float t[32][33];
  int bn = blockIdx.x, bk = blockIdx.y;
  int tx = threadIdx.x & 31, ty = threadIdx.x >> 5;
#pragma unroll
  for (int i = 0; i < 4; ++i)
    t[ty + i*8][tx] = W[(size_t)(bk*32 + ty + i*8) * N + bn*32 + tx];
  __syncthreads();
#pragma unroll
  for (int i = 0; i < 4; ++i)
    Wt[(size_t)(bn*32 + ty + i*8) * K + bk*32 + tx] = f2bf(t[tx][ty + i*8]);
}

// ------------------------------------------------------------------- GEMM
// C[M][N] = A[M][K](bf16) @ Bt[N][K](bf16)^T  (+bias)(+resid f32)(relu)
// 128x128 block tile, BK=32, 4 waves of 64x64, mfma_f32_16x16x32_bf16.
// Staging via global_load_lds width=16: thread ci's LDS slot is element ci*8
// (byte ci*16) == wave-uniform base + lane*16  -> linear-dest constraint OK.
template<int BIAS, int RELU, int RESID, int OUTBF16>
__global__ __launch_bounds__(256) void gemm_kernel(
    const ushort_t* __restrict__ A, const ushort_t* __restrict__ Bt,
    const float* __restrict__ bias, const float* __restrict__ resid,
    void* __restrict__ outp, int M, int N, int K) {
  __shared__ __align__(16) ushort_t As[128*32];
  __shared__ __align__(16) ushort_t Bs[128*32];
  int bn = blockIdx.x, bm = blockIdx.y;
  int tid = threadIdx.x;
  int lane = tid & 63, wid = tid >> 6;
  int wr = (wid >> 1) * 64, wc = (wid & 1) * 64;
  int r = lane & 15, g = lane >> 4;
  // staging coords for this thread (constant across K-tiles)
  int srow = tid >> 2, scc = (tid & 3) * 8;     // ci = tid   (p=0)
  int srow2 = srow + 64;                         // ci = tid+256 (p=1)
  f32x4 acc[4][4] = {};
  int nk = K >> 5;
  for (int kt = 0; kt < nk; ++kt) {
    gload_lds16(&A[(size_t)(bm*128 + srow)  * K + kt*32 + scc], &As[tid*8]);
    gload_lds16(&A[(size_t)(bm*128 + srow2) * K + kt*32 + scc], &As[(tid+256)*8]);
    gload_lds16(&Bt[(size_t)(bn*128 + srow)  * K + kt*32 + scc], &Bs[tid*8]);
    gload_lds16(&Bt[(size_t)(bn*128 + srow2) * K + kt*32 + scc], &Bs[(tid+256)*8]);
    __syncthreads();
    bf16x8 af[4], bfv[4];
#pragma unroll
    for (int m = 0; m < 4; ++m)
      af[m] = *(const bf16x8*)&As[(wr + m*16 + r)*32 + g*8];
#pragma unroll
    for (int n = 0; n < 4; ++n)
      bfv[n] = *(const bf16x8*)&Bs[(wc + n*16 + r)*32 + g*8];
#pragma unroll
    for (int m = 0; m < 4; ++m)
#pragma unroll
      for (int n = 0; n < 4; ++n)
        acc[m][n] = __builtin_amdgcn_mfma_f32_16x16x32_bf16(
            af[m], bfv[n], acc[m][n], 0, 0, 0);
    __syncthreads();
  }
#pragma unroll
  for (int m = 0; m < 4; ++m)
#pragma unroll
    for (int n = 0; n < 4; ++n)
#pragma unroll
      for (int e = 0; e < 4; ++e) {
        int row = bm*128 + wr + m*16 + g*4 + e;
        int col = bn*128 + wc + n*16 + r;
        float v = acc[m][n][e];
        if (BIAS)  v += bias[col];
        if (RESID) v += resid[(size_t)row * N + col];
        if (RELU)  v = fmaxf(v, 0.0f);
        if (OUTBF16) ((ushort_t*)outp)[(size_t)row * N + col] = f2bf(v);
        else         ((float*)outp)[(size_t)row * N + col]    = v;
      }
}

// -------------------------------------------------------- flash attention
// One block = one (b, h, 64-query tile). 4 waves x 16 queries.
// q,k,v,o are bf16 [B][T][C] with head h at cols h*64..h*64+63.
__global__ __launch_bounds__(256) void attn_kernel(
    const ushort_t* __restrict__ q, const ushort_t* __restrict__ k,
    const ushort_t* __restrict__ v, ushort_t* __restrict__ o) {
  int bid = blockIdx.x;
  int qb = bid & 31;          // T/64 = 32
  int hh = (bid >> 5) & 15;
  int bb = bid >> 9;
  __shared__ __align__(16) ushort_t Qs[64*64], Ks[64*64], Vt[64*64];
  __shared__ __align__(16) ushort_t Ps[4][16*64];
  int tid = threadIdx.x, lane = tid & 63, w = tid >> 6;
  int r = lane & 15, g = lane >> 4;
#pragma unroll
  for (int p = 0; p < 2; ++p) {
    int ci = p*256 + tid;
    int row = ci >> 3, c8 = (ci & 7) * 8;
    *(uint4*)&Qs[row*64 + c8] =
        *(const uint4*)&q[((size_t)(bb*T_ + qb*64 + row))*C_ + hh*64 + c8];
  }
  f32x4 O[4] = {};
  float mrow[4], lrow[4];
#pragma unroll
  for (int e = 0; e < 4; ++e) { mrow[e] = -1e30f; lrow[e] = 0.f; }
  for (int kb = 0; kb <= qb; ++kb) {
    __syncthreads();   // prev iter's LDS reads done (and Qs ready at kb=0)
#pragma unroll
    for (int p = 0; p < 2; ++p) {
      int ci = p*256 + tid;
      int row = ci >> 3, c8 = (ci & 7) * 8;
      *(uint4*)&Ks[row*64 + c8] =
          *(const uint4*)&k[((size_t)(bb*T_ + kb*64 + row))*C_ + hh*64 + c8];
    }
#pragma unroll
    for (int i = 0; i < 16; ++i) {
      int ci = i*256 + tid;
      int key = ci >> 6, d = ci & 63;
      Vt[d*64 + key] = v[((size_t)(bb*T_ + kb*64 + key))*C_ + hh*64 + d];
    }
    __syncthreads();
    // S = (Q K^T) for this wave's 16 queries x 64 keys
    f32x4 s[4] = {};
#pragma unroll
    for (int ks = 0; ks < 2; ++ks) {
      bf16x8 aq = *(const bf16x8*)&Qs[(w*16 + r)*64 + ks*32 + g*8];
#pragma unroll
      for (int n = 0; n < 4; ++n) {
        bf16x8 bk = *(const bf16x8*)&Ks[(n*16 + r)*64 + ks*32 + g*8];
        s[n] = __builtin_amdgcn_mfma_f32_16x16x32_bf16(aq, bk, s[n], 0, 0, 0);
      }
    }
    int qrow0 = qb*64 + w*16 + g*4;
#pragma unroll
    for (int e = 0; e < 4; ++e) {
      float mx = -1e30f;
#pragma unroll
      for (int n = 0; n < 4; ++n) {
        float sv = s[n][e] * 0.125f;                 // 1/sqrt(64)
        if (kb*64 + n*16 + r > qrow0 + e) sv = -1e30f; // causal mask
        s[n][e] = sv;
        mx = fmaxf(mx, sv);
      }
#pragma unroll
      for (int off = 1; off < 16; off <<= 1)
        mx = fmaxf(mx, __shfl_xor(mx, off, 16));
      float mnew = fmaxf(mrow[e], mx);
      float sf = __expf(mrow[e] - mnew);
      mrow[e] = mnew;
      float rsum = 0.f;
#pragma unroll
      for (int n = 0; n < 4; ++n) {
        float p = __expf(s[n][e] - mnew);
        rsum += p;
        Ps[w][(g*4 + e)*64 + n*16 + r] = f2bf(p);
      }
#pragma unroll
      for (int off = 1; off < 16; off <<= 1)
        rsum += __shfl_xor(rsum, off, 16);
      lrow[e] = lrow[e] * sf + rsum;
#pragma unroll
      for (int dn = 0; dn < 4; ++dn) O[dn][e] *= sf;
    }
    __syncthreads();   // Ps visible
#pragma unroll
    for (int ks = 0; ks < 2; ++ks) {
      bf16x8 ap = *(const bf16x8*)&Ps[w][r*64 + ks*32 + g*8];
#pragma unroll
      for (int dn = 0; dn < 4; ++dn) {
        bf16x8 bv = *(const bf16x8*)&Vt[(dn*16 + r)*64 + ks*32 + g*8];
        O[dn] = __builtin_amdgcn_mfma_f32_16x16x32_bf16(ap, bv, O[dn], 0, 0, 0);
      }
    }
  }
#pragma unroll
  for (int dn = 0; dn < 4; ++dn)
#pragma unroll
    for (int e = 0; e < 4; ++e) {
      int tok = qb*64 + w*16 + g*4 + e;
      int col = hh*64 + dn*16 + r;
      o[((size_t)(bb*T_ + tok))*C_ + col] = f2bf(O[dn][e] / lrow[e]);
    }
}

// ----------------------------------------------------------------- launch
extern "C" void kernel_launch(void* const* d_in, const int* in_sizes, int n_in,
                              void* d_out, int out_size, void* d_ws, size_t ws_size,
                              hipStream_t stream) {
  const float* x    = (const float*)d_in[0];
  const float* Wq   = (const float*)d_in[1];
  const float* Wk   = (const float*)d_in[2];
  const float* Wv   = (const float*)d_in[3];
  const float* Wo   = (const float*)d_in[4];
  const float* bo   = (const float*)d_in[5];
  const float* ln1g = (const float*)d_in[6];
  const float* ln1b = (const float*)d_in[7];
  const float* ln2g = (const float*)d_in[8];
  const float* ln2b = (const float*)d_in[9];
  const float* W1   = (const float*)d_in[10];
  const float* b1   = (const float*)d_in[11];
  const float* W2   = (const float*)d_in[12];
  const float* b2   = (const float*)d_in[13];

  char* ws = (char*)d_ws;
  // layout (MB offsets): h@0, q@8, k@16, v@24 | ff@0 (aliases h..v, 32MB)
  // attn@32, x2@40 (f32,16MB), h2@56, weights@64..88
  ushort_t* h    = (ushort_t*)(ws + ((size_t)0  << 20));
  ushort_t* qd   = (ushort_t*)(ws + ((size_t)8  << 20));
  ushort_t* kd   = (ushort_t*)(ws + ((size_t)16 << 20));
  ushort_t* vd   = (ushort_t*)(ws + ((size_t)24 << 20));
  ushort_t* ff   = (ushort_t*)(ws + ((size_t)0  << 20));
  ushort_t* attn = (ushort_t*)(ws + ((size_t)32 << 20));
  float*    x2   = (float*)   (ws + ((size_t)40 << 20));
  ushort_t* h2   = (ushort_t*)(ws + ((size_t)56 << 20));
  ushort_t* wqt  = (ushort_t*)(ws + ((size_t)64 << 20));
  ushort_t* wkt  = (ushort_t*)(ws + ((size_t)66 << 20));
  ushort_t* wvt  = (ushort_t*)(ws + ((size_t)68 << 20));
  ushort_t* wot  = (ushort_t*)(ws + ((size_t)70 << 20));
  ushort_t* w1t  = (ushort_t*)(ws + ((size_t)72 << 20));
  ushort_t* w2t  = (ushort_t*)(ws + ((size_t)80 << 20));
  float* out = (float*)d_out;

  // weight transpose+cast: W [K][N] -> Wt [N][K] bf16
  tcast_kernel<<<dim3(32, 32),  256, 0, stream>>>(Wq, wqt, 1024, 1024);
  tcast_kernel<<<dim3(32, 32),  256, 0, stream>>>(Wk, wkt, 1024, 1024);
  tcast_kernel<<<dim3(32, 32),  256, 0, stream>>>(Wv, wvt, 1024, 1024);
  tcast_kernel<<<dim3(32, 32),  256, 0, stream>>>(Wo, wot, 1024, 1024);
  tcast_kernel<<<dim3(128, 32), 256, 0, stream>>>(W1, w1t, 1024, 4096);
  tcast_kernel<<<dim3(32, 128), 256, 0, stream>>>(W2, w2t, 4096, 1024);

  lnorm_kernel<<<M_, 256, 0, stream>>>(x, ln1g, ln1b, h);

  gemm_kernel<0,0,0,1><<<dim3(8, 32), 256, 0, stream>>>(h, wqt, nullptr, nullptr, qd, M_, C_, C_);
  gemm_kernel<0,0,0,1><<<dim3(8, 32), 256, 0, stream>>>(h, wkt, nullptr, nullptr, kd, M_, C_, C_);
  gemm_kernel<0,0,0,1><<<dim3(8, 32), 256, 0, stream>>>(h, wvt, nullptr, nullptr, vd, M_, C_, C_);

  attn_kernel<<<B_*H_*(T_/64), 256, 0, stream>>>(qd, kd, vd, attn);

  // x2 = x + attn @ Wo + bo   (f32)
  gemm_kernel<1,0,1,0><<<dim3(8, 32), 256, 0, stream>>>(attn, wot, bo, x, x2, M_, C_, C_);

  lnorm_kernel<<<M_, 256, 0, stream>>>(x2, ln2g, ln2b, h2);

  // ff = relu(h2 @ W1 + b1)  (bf16)
  gemm_kernel<1,1,0,1><<<dim3(32, 32), 256, 0, stream>>>(h2, w1t, b1, nullptr, ff, M_, FF_, C_);

  // out = x2 + ff @ W2 + b2  (f32)
  gemm_kernel<1,0,1,0><<<dim3(8, 32), 256, 0, stream>>>(ff, w2t, b2, x2, out, M_, C_, FF_);
}

// Round 4
// 493.419 us; speedup vs baseline: 1.5765x; 1.5765x over previous
//
#include <hip/hip_runtime.h>
#include <hip/hip_bf16.h>
#include <stdint.h>

#define B_  2
#define T_  2048
#define C_  1024
#define H_  16
#define HD_ 64
#define M_  4096   // B*T
#define FF_ 4096

typedef unsigned short ushort_t;
typedef __bf16 bf16x8 __attribute__((ext_vector_type(8)));
typedef float  f32x4  __attribute__((ext_vector_type(4)));

__device__ inline ushort_t f2bf(float f) {
  uint32_t u = __builtin_bit_cast(uint32_t, f);
  u += 0x7fffu + ((u >> 16) & 1u);
  return (ushort_t)(u >> 16);
}

// async global->LDS, 16B per lane (dwordx4 variant)
__device__ inline void gload_lds16(const void* g, void* l) {
  __builtin_amdgcn_global_load_lds(
      (const __attribute__((address_space(1))) uint32_t*)g,
      (__attribute__((address_space(3))) uint32_t*)l, 16, 0, 0);
}

// LDS swizzles for 64-col bf16 tiles (128B rows, 8x16B slots per row).
// QK-swizzle: slot ^= row&7  (conflict-free b128 reads at row=..+r)
__device__ inline int qswz(int row, int byte_in_row) {
  return row * 128 + (byte_in_row ^ ((row & 7) << 4));
}
// V-swizzle: slot ^= (row>>3)&7  (<=2-way for transposing 2B writes AND b128 reads)
__device__ inline int vswz(int row, int byte_in_row) {
  return row * 128 + (byte_in_row ^ (((row >> 3) & 7) << 4));
}

// ---------------------------------------------------------------- LayerNorm
__global__ __launch_bounds__(256) void lnorm_kernel(
    const float* __restrict__ x, const float* __restrict__ g,
    const float* __restrict__ b, ushort_t* __restrict__ o) {
  int row = blockIdx.x;
  int tid = threadIdx.x;
  const float4* xr = (const float4*)(x + (size_t)row * C_);
  float4 xv = xr[tid];
  float s  = xv.x + xv.y + xv.z + xv.w;
  float s2 = xv.x*xv.x + xv.y*xv.y + xv.z*xv.z + xv.w*xv.w;
#pragma unroll
  for (int off = 32; off; off >>= 1) {
    s  += __shfl_down(s,  off);
    s2 += __shfl_down(s2, off);
  }
  __shared__ float rs[4], rq[4];
  int wid = tid >> 6;
  if ((tid & 63) == 0) { rs[wid] = s; rq[wid] = s2; }
  __syncthreads();
  float tot  = rs[0] + rs[1] + rs[2] + rs[3];
  float tot2 = rq[0] + rq[1] + rq[2] + rq[3];
  float mu   = tot * (1.0f / C_);
  float var  = tot2 * (1.0f / C_) - mu * mu;
  float rstd = rsqrtf(var + 1e-5f);
  float4 gv = ((const float4*)g)[tid];
  float4 bv = ((const float4*)b)[tid];
  float y0 = (xv.x - mu) * rstd * gv.x + bv.x;
  float y1 = (xv.y - mu) * rstd * gv.y + bv.y;
  float y2 = (xv.z - mu) * rstd * gv.z + bv.z;
  float y3 = (xv.w - mu) * rstd * gv.w + bv.w;
  uint2 pk;
  pk.x = (uint32_t)f2bf(y0) | ((uint32_t)f2bf(y1) << 16);
  pk.y = (uint32_t)f2bf(y2) | ((uint32_t)f2bf(y3) << 16);
  *(uint2*)(o + (size_t)row * C_ + tid * 4) = pk;
}

// ------------------------------------------- transpose + f32->bf16 cast of W
// W [K][N] f32  ->  Wt [N][K] bf16
__global__ __launch_bounds__(256) void tcast_kernel(
    const float* __restrict__ W, ushort_t* __restrict__ Wt, int K, int N) {
  __shared__ float t[32][33];
  int bn = blockIdx.x, bk = blockIdx.y;
  int tx = threadIdx.x & 31, ty = threadIdx.x >> 5;
#pragma unroll
  for (int i = 0; i < 4; ++i)
    t[ty + i*8][tx] = W[(size_t)(bk*32 + ty + i*8) * N + bn*32 + tx];
  __syncthreads();
#pragma unroll
  for (int i = 0; i < 4; ++i)
    Wt[(size_t)(bn*32 + ty + i*8) * K + bk*32 + tx] = f2bf(t[tx][ty + i*8]);
}

// ------------------------------------------------------------------- GEMM
// C[M][N] = A[M][K](bf16) @ Bt[N][K](bf16)^T  (+bias)(+resid f32)(relu)
// 128x128 block tile, BK=32, 4 waves of 64x64, mfma_f32_16x16x32_bf16.
// Staging via global_load_lds width=16 (linear dest, verified R3).
template<int BIAS, int RELU, int RESID, int OUTBF16>
__global__ __launch_bounds__(256) void gemm_kernel(
    const ushort_t* __restrict__ A, const ushort_t* __restrict__ Bt,
    const float* __restrict__ bias, const float* __restrict__ resid,
    void* __restrict__ outp, int M, int N, int K) {
  __shared__ __align__(16) ushort_t As[128*32];
  __shared__ __align__(16) ushort_t Bs[128*32];
  int bn = blockIdx.x, bm = blockIdx.y;
  int tid = threadIdx.x;
  int lane = tid & 63, wid = tid >> 6;
  int wr = (wid >> 1) * 64, wc = (wid & 1) * 64;
  int r = lane & 15, g = lane >> 4;
  int srow = tid >> 2, scc = (tid & 3) * 8;
  int srow2 = srow + 64;
  f32x4 acc[4][4] = {};
  int nk = K >> 5;
  for (int kt = 0; kt < nk; ++kt) {
    gload_lds16(&A[(size_t)(bm*128 + srow)  * K + kt*32 + scc], &As[tid*8]);
    gload_lds16(&A[(size_t)(bm*128 + srow2) * K + kt*32 + scc], &As[(tid+256)*8]);
    gload_lds16(&Bt[(size_t)(bn*128 + srow)  * K + kt*32 + scc], &Bs[tid*8]);
    gload_lds16(&Bt[(size_t)(bn*128 + srow2) * K + kt*32 + scc], &Bs[(tid+256)*8]);
    __syncthreads();
    bf16x8 af[4], bfv[4];
#pragma unroll
    for (int m = 0; m < 4; ++m)
      af[m] = *(const bf16x8*)&As[(wr + m*16 + r)*32 + g*8];
#pragma unroll
    for (int n = 0; n < 4; ++n)
      bfv[n] = *(const bf16x8*)&Bs[(wc + n*16 + r)*32 + g*8];
#pragma unroll
    for (int m = 0; m < 4; ++m)
#pragma unroll
      for (int n = 0; n < 4; ++n)
        acc[m][n] = __builtin_amdgcn_mfma_f32_16x16x32_bf16(
            af[m], bfv[n], acc[m][n], 0, 0, 0);
    __syncthreads();
  }
#pragma unroll
  for (int m = 0; m < 4; ++m)
#pragma unroll
    for (int n = 0; n < 4; ++n)
#pragma unroll
      for (int e = 0; e < 4; ++e) {
        int row = bm*128 + wr + m*16 + g*4 + e;
        int col = bn*128 + wc + n*16 + r;
        float v = acc[m][n][e];
        if (BIAS)  v += bias[col];
        if (RESID) v += resid[(size_t)row * N + col];
        if (RELU)  v = fmaxf(v, 0.0f);
        if (OUTBF16) ((ushort_t*)outp)[(size_t)row * N + col] = f2bf(v);
        else         ((float*)outp)[(size_t)row * N + col]    = v;
      }
}

// -------------------------------------------------------- flash attention
// One block = one (b, h, 64-query tile). 4 waves x 16 queries.
// q,k,v point into the fused qkv buffer [B*T][ldq] (ldq=3072).
// All LDS tiles XOR-swizzled; heavy q-tiles launch first (LPT).
__global__ __launch_bounds__(256) void attn_kernel(
    const ushort_t* __restrict__ q, const ushort_t* __restrict__ k,
    const ushort_t* __restrict__ v, ushort_t* __restrict__ o, int ldq) {
  int bid = blockIdx.x;
  int qb = 31 - (bid & 31);   // LPT: heavy tiles first
  int hh = (bid >> 5) & 15;
  int bb = bid >> 9;
  __shared__ __align__(16) ushort_t Qs[64*64], Ks[64*64], Vt[64*64];
  __shared__ __align__(16) ushort_t Ps[4][16*64];
  int tid = threadIdx.x, lane = tid & 63, w = tid >> 6;
  int r = lane & 15, g = lane >> 4;
#pragma unroll
  for (int p = 0; p < 2; ++p) {
    int ci = p*256 + tid;
    int row = ci >> 3, c8 = (ci & 7) * 8;
    *(uint4*)((char*)Qs + qswz(row, c8*2)) =
        *(const uint4*)&q[((size_t)(bb*T_ + qb*64 + row))*ldq + hh*64 + c8];
  }
  f32x4 O[4] = {};
  float mrow[4], lrow[4];
#pragma unroll
  for (int e = 0; e < 4; ++e) { mrow[e] = -1e30f; lrow[e] = 0.f; }
  for (int kb = 0; kb <= qb; ++kb) {
    __syncthreads();   // prev iter's LDS reads done (and Qs ready at kb=0)
#pragma unroll
    for (int p = 0; p < 2; ++p) {
      int ci = p*256 + tid;
      int row = ci >> 3, c8 = (ci & 7) * 8;
      *(uint4*)((char*)Ks + qswz(row, c8*2)) =
          *(const uint4*)&k[((size_t)(bb*T_ + kb*64 + row))*ldq + hh*64 + c8];
      // V: load 8 consecutive d for one key, scatter into transposed Vt
      int key = row;
      uint4 vv = *(const uint4*)&v[((size_t)(bb*T_ + kb*64 + key))*ldq + hh*64 + c8];
      ushort_t tmp[8];
      *(uint4*)tmp = vv;
#pragma unroll
      for (int j = 0; j < 8; ++j)
        *(ushort_t*)((char*)Vt + vswz(c8 + j, key*2)) = tmp[j];
    }
    __syncthreads();
    // S = (Q K^T) for this wave's 16 queries x 64 keys
    f32x4 s[4] = {};
#pragma unroll
    for (int ks = 0; ks < 2; ++ks) {
      bf16x8 aq = *(const bf16x8*)((char*)Qs + qswz(w*16 + r, (ks*32 + g*8)*2));
#pragma unroll
      for (int n = 0; n < 4; ++n) {
        bf16x8 bk = *(const bf16x8*)((char*)Ks + qswz(n*16 + r, (ks*32 + g*8)*2));
        s[n] = __builtin_amdgcn_mfma_f32_16x16x32_bf16(aq, bk, s[n], 0, 0, 0);
      }
    }
    int qrow0 = qb*64 + w*16 + g*4;
#pragma unroll
    for (int e = 0; e < 4; ++e) {
      float mx = -1e30f;
#pragma unroll
      for (int n = 0; n < 4; ++n) {
        float sv = s[n][e] * 0.125f;                 // 1/sqrt(64)
        if (kb*64 + n*16 + r > qrow0 + e) sv = -1e30f; // causal mask
        s[n][e] = sv;
        mx = fmaxf(mx, sv);
      }
#pragma unroll
      for (int off = 1; off < 16; off <<= 1)
        mx = fmaxf(mx, __shfl_xor(mx, off, 16));
      float mnew = fmaxf(mrow[e], mx);
      float sf = __expf(mrow[e] - mnew);
      mrow[e] = mnew;
      float rsum = 0.f;
#pragma unroll
      for (int n = 0; n < 4; ++n) {
        float p = __expf(s[n][e] - mnew);
        rsum += p;
        *(ushort_t*)((char*)&Ps[w][0] + qswz(g*4 + e, (n*16 + r)*2)) = f2bf(p);
      }
#pragma unroll
      for (int off = 1; off < 16; off <<= 1)
        rsum += __shfl_xor(rsum, off, 16);
      lrow[e] = lrow[e] * sf + rsum;
#pragma unroll
      for (int dn = 0; dn < 4; ++dn) O[dn][e] *= sf;
    }
    __syncthreads();   // Ps visible
#pragma unroll
    for (int ks = 0; ks < 2; ++ks) {
      bf16x8 ap = *(const bf16x8*)((char*)&Ps[w][0] + qswz(r, (ks*32 + g*8)*2));
#pragma unroll
      for (int dn = 0; dn < 4; ++dn) {
        bf16x8 bv = *(const bf16x8*)((char*)Vt + vswz(dn*16 + r, (ks*32 + g*8)*2));
        O[dn] = __builtin_amdgcn_mfma_f32_16x16x32_bf16(ap, bv, O[dn], 0, 0, 0);
      }
    }
  }
#pragma unroll
  for (int dn = 0; dn < 4; ++dn)
#pragma unroll
    for (int e = 0; e < 4; ++e) {
      int tok = qb*64 + w*16 + g*4 + e;
      int col = hh*64 + dn*16 + r;
      o[((size_t)(bb*T_ + tok))*C_ + col] = f2bf(O[dn][e] / lrow[e]);
    }
}

// ----------------------------------------------------------------- launch
extern "C" void kernel_launch(void* const* d_in, const int* in_sizes, int n_in,
                              void* d_out, int out_size, void* d_ws, size_t ws_size,
                              hipStream_t stream) {
  const float* x    = (const float*)d_in[0];
  const float* Wq   = (const float*)d_in[1];
  const float* Wk   = (const float*)d_in[2];
  const float* Wv   = (const float*)d_in[3];
  const float* Wo   = (const float*)d_in[4];
  const float* bo   = (const float*)d_in[5];
  const float* ln1g = (const float*)d_in[6];
  const float* ln1b = (const float*)d_in[7];
  const float* ln2g = (const float*)d_in[8];
  const float* ln2b = (const float*)d_in[9];
  const float* W1   = (const float*)d_in[10];
  const float* b1   = (const float*)d_in[11];
  const float* W2   = (const float*)d_in[12];
  const float* b2   = (const float*)d_in[13];

  char* ws = (char*)d_ws;
  // layout (MB offsets): h@0 (8MB), qkv@8 (24MB) | ff@0 aliases both (32MB)
  // attn@32 (8MB), x2@40 (f32,16MB), h2@56 (8MB), weights@64..88
  ushort_t* h    = (ushort_t*)(ws + ((size_t)0  << 20));
  ushort_t* qkv  = (ushort_t*)(ws + ((size_t)8  << 20));
  ushort_t* ff   = (ushort_t*)(ws + ((size_t)0  << 20));
  ushort_t* attn = (ushort_t*)(ws + ((size_t)32 << 20));
  float*    x2   = (float*)   (ws + ((size_t)40 << 20));
  ushort_t* h2   = (ushort_t*)(ws + ((size_t)56 << 20));
  ushort_t* wqt  = (ushort_t*)(ws + ((size_t)64 << 20));  // [3072][1024] combined
  ushort_t* wkt  = (ushort_t*)(ws + ((size_t)66 << 20));
  ushort_t* wvt  = (ushort_t*)(ws + ((size_t)68 << 20));
  ushort_t* wot  = (ushort_t*)(ws + ((size_t)70 << 20));
  ushort_t* w1t  = (ushort_t*)(ws + ((size_t)72 << 20));
  ushort_t* w2t  = (ushort_t*)(ws + ((size_t)80 << 20));
  float* out = (float*)d_out;

  // weight transpose+cast: W [K][N] -> Wt [N][K] bf16
  tcast_kernel<<<dim3(32, 32),  256, 0, stream>>>(Wq, wqt, 1024, 1024);
  tcast_kernel<<<dim3(32, 32),  256, 0, stream>>>(Wk, wkt, 1024, 1024);
  tcast_kernel<<<dim3(32, 32),  256, 0, stream>>>(Wv, wvt, 1024, 1024);
  tcast_kernel<<<dim3(32, 32),  256, 0, stream>>>(Wo, wot, 1024, 1024);
  tcast_kernel<<<dim3(128, 32), 256, 0, stream>>>(W1, w1t, 1024, 4096);
  tcast_kernel<<<dim3(32, 128), 256, 0, stream>>>(W2, w2t, 4096, 1024);

  lnorm_kernel<<<M_, 256, 0, stream>>>(x, ln1g, ln1b, h);

  // fused QKV: qkv[M][3072] = h @ [Wq|Wk|Wv]  (wqt/wkt/wvt contiguous)
  gemm_kernel<0,0,0,1><<<dim3(24, 32), 256, 0, stream>>>(h, wqt, nullptr, nullptr, qkv, M_, 3*C_, C_);

  attn_kernel<<<B_*H_*(T_/64), 256, 0, stream>>>(qkv, qkv + C_, qkv + 2*C_, attn, 3*C_);

  // x2 = x + attn @ Wo + bo   (f32)
  gemm_kernel<1,0,1,0><<<dim3(8, 32), 256, 0, stream>>>(attn, wot, bo, x, x2, M_, C_, C_);

  lnorm_kernel<<<M_, 256, 0, stream>>>(x2, ln2g, ln2b, h2);

  // ff = relu(h2 @ W1 + b1)  (bf16)
  gemm_kernel<1,1,0,1><<<dim3(32, 32), 256, 0, stream>>>(h2, w1t, b1, nullptr, ff, M_, FF_, C_);

  // out = x2 + ff @ W2 + b2  (f32)
  gemm_kernel<1,0,1,0><<<dim3(8, 32), 256, 0, stream>>>(ff, w2t, b2, x2, out, M_, C_, FF_);
}